// Round 5
// baseline (737.934 us; speedup 1.0000x reference)
//
#include <hip/hip_runtime.h>
#include <hip/hip_bf16.h>

#define AS1 __attribute__((address_space(1)))
#define AS3 __attribute__((address_space(3)))

typedef __bf16 bf16x8_t __attribute__((ext_vector_type(8)));
typedef float f32x4_t __attribute__((ext_vector_type(4)));
typedef unsigned short ushort_t;
typedef unsigned int uint_t;

static __device__ __forceinline__ ushort_t f2b(float f) {
    __hip_bfloat16 h = __float2bfloat16(f);
    return __builtin_bit_cast(unsigned short, h);
}
static __device__ __forceinline__ float b2f(ushort_t u) {
    return __uint_as_float((uint_t)u << 16);
}

#define EPI_BIAS 1
#define EPI_RELU 2
#define EPI_PART 8
#define EPI_OUTB 16

// ---------------------------------------------------------------- software grid barrier
// Sense-reversing, device-scope (G12/G16): release fence -> arrive -> last
// resets cnt and bumps gen -> spinners poll gen via coherent atomic ->
// acquire fence. __threadfence() is agent scope (L2 wb/inv) so cross-XCD
// data written before the barrier is visible after it.
static __device__ __forceinline__ void gsync(uint_t* cnt, uint_t* gen, uint_t nb) {
    __syncthreads();                       // drains each wave's vmcnt before s_barrier
    if (threadIdx.x == 0) {
        __threadfence();                   // release: write back this XCD's L2
        uint_t g = atomicAdd(gen, 0u);
        if (atomicAdd(cnt, 1u) == nb - 1u) {
            __threadfence();
            atomicExch(cnt, 0u);
            __threadfence();               // reset visible before generation bump
            atomicAdd(gen, 1u);
        } else {
            while (atomicAdd(gen, 0u) == g) __builtin_amdgcn_s_sleep(8);
        }
        __threadfence();                   // acquire: invalidate stale L1/L2
    }
    __syncthreads();
}

// ---------------------------------------------------------------- cast phase
static __device__ __forceinline__ void cast_arr(const float* __restrict__ src,
                                                ushort_t* __restrict__ dst,
                                                int n4, int tid, int nthr) {
    for (int i = tid; i < n4; i += nthr) {
        float4 v = ((const float4*)src)[i];
        ushort4 o;
        o.x = f2b(v.x); o.y = f2b(v.y); o.z = f2b(v.z); o.w = f2b(v.w);
        ((ushort4*)dst)[i] = o;
    }
}

// ---------------------------------------------------------------- bf16 MFMA GEMM tile (r0-proven body)
// 128x128 tile, BK=64, 4 waves, 2-barrier K-loop. C = A @ B^T (B stored NxK).
// LDS rows 64 elems; XOR-swizzled global 16B chunk staging (conflict-free).
// Split-K over z writes bf16 partials. lid decode identical to r0 grids.
template <int F>
static __device__ void gemm_tile(ushort_t* la, ushort_t* lb,
                                 const ushort_t* __restrict__ A,
                                 const ushort_t* __restrict__ B,
                                 const float* __restrict__ bias,
                                 ushort_t* p0, ushort_t* p1, ushort_t* p2, ushort_t* p3,
                                 ushort_t* __restrict__ outb,
                                 int N, int Kc, int ld,
                                 int lid, int nx, int ny, int nz, int t) {
    const int xcd = lid & 7;
    const int slot = lid >> 3;
    const int n_i = slot % nx;
    const int rest = slot / nx;
    const int z = rest % nz;
    const int m_i = xcd * (ny >> 3) + rest / nz;

    const int n0 = n_i * 128;
    const int m0 = m_i * 128;
    const int k0 = z * Kc;
    const int lane = t & 63;
    const int w = t >> 6;
    const int wr = w >> 1, wc = w & 1;
    const int r16 = lane & 15, kq = lane >> 4;

    f32x4_t acc[4][4] = {};

    size_t aoff[4], boff[4];
#pragma unroll
    for (int p = 0; p < 4; ++p) {
        const int c = t + 256 * p;
        const int row = c >> 3, cc = c & 7;
        const int gcol = (cc ^ (row & 7)) * 8;
        aoff[p] = (size_t)(m0 + row) * ld + gcol + k0;
        boff[p] = (size_t)(n0 + row) * ld + gcol + k0;
    }

    for (int kk = 0; kk < Kc; kk += 64) {
#pragma unroll
        for (int p = 0; p < 4; ++p) {
            __builtin_amdgcn_global_load_lds((AS1 void*)(A + aoff[p] + kk),
                                             (AS3 void*)(la + (t + 256 * p) * 8), 16, 0, 0);
            __builtin_amdgcn_global_load_lds((AS1 void*)(B + boff[p] + kk),
                                             (AS3 void*)(lb + (t + 256 * p) * 8), 16, 0, 0);
        }
        __syncthreads();
#pragma unroll
        for (int half = 0; half < 2; ++half) {
            const int sw = ((half * 4 + kq) ^ (r16 & 7)) * 8;
            bf16x8_t af[4], bfr[4];
#pragma unroll
            for (int mi = 0; mi < 4; ++mi)
                af[mi] = *(const bf16x8_t*)(la + (wr * 64 + mi * 16 + r16) * 64 + sw);
#pragma unroll
            for (int ni = 0; ni < 4; ++ni)
                bfr[ni] = *(const bf16x8_t*)(lb + (wc * 64 + ni * 16 + r16) * 64 + sw);
#pragma unroll
            for (int mi = 0; mi < 4; ++mi)
#pragma unroll
                for (int ni = 0; ni < 4; ++ni)
                    acc[mi][ni] = __builtin_amdgcn_mfma_f32_16x16x32_bf16(af[mi], bfr[ni], acc[mi][ni], 0, 0, 0);
        }
        __syncthreads();
    }

    ushort_t* po;
    if (F & EPI_PART) {
        ushort_t* lo = (z & 1) ? p1 : p0;
        ushort_t* hi = (z & 1) ? p3 : p2;
        po = (z & 2) ? hi : lo;
    } else {
        po = outb;
    }
#pragma unroll
    for (int mi = 0; mi < 4; ++mi) {
#pragma unroll
        for (int ni = 0; ni < 4; ++ni) {
            const int row = m0 + wr * 64 + mi * 16 + kq * 4;
            const int col = n0 + wc * 64 + ni * 16 + r16;
            float bv = (F & EPI_BIAS) ? bias[col] : 0.f;
#pragma unroll
            for (int i = 0; i < 4; ++i) {
                float v = acc[mi][ni][i] + bv;
                const size_t off = (size_t)(row + i) * N + col;
                if (F & EPI_RELU) v = fmaxf(v, 0.f);
                po[off] = f2b(v);
            }
        }
    }
}

// ---------------------------------------------------------------- MFMA banded flash attention tile (r0-proven body)
// qkv: (B*S, 3072) bf16 rows [q | k | v]; lid decodes the old dim3(32,16,2).
static __device__ void flash_tile(ushort_t* lk, ushort_t* lv, ushort_t* lp,
                                  const ushort_t* __restrict__ qkv,
                                  ushort_t* __restrict__ attn,
                                  int lid, int t) {
    const int S = 2048;
    const int h = (lid >> 5) & 15, bb = lid >> 9;
    const int q0 = (lid & 31) * 64;
    const int w = t >> 6, lane = t & 63;
    const int r16 = lane & 15, g = lane >> 4;

    const ushort_t* base = qkv + (size_t)bb * S * 3072 + (size_t)h * 64;

    bf16x8_t qa[2];
    {
        const ushort_t* qrow = base + (size_t)(q0 + 16 * w + r16) * 3072;
        qa[0] = *(const bf16x8_t*)(qrow + g * 8);
        qa[1] = *(const bf16x8_t*)(qrow + 32 + g * 8);
    }

    f32x4_t O[4] = {};
    float mrow[4] = {-1e30f, -1e30f, -1e30f, -1e30f};
    float lrow[4] = {0.f, 0.f, 0.f, 0.f};

    for (int it = 0; it < 5; ++it) {
        const int kt0 = q0 - 128 + 64 * it;
        if (kt0 < 0 || kt0 >= S) continue;

#pragma unroll
        for (int pass = 0; pass < 2; ++pass) {
            const int c = t + 256 * pass;
            const int key = c >> 3, dc = c & 7;
            const ushort_t* src = base + (size_t)(kt0 + key) * 3072 + dc * 8;
            uint4 kk = *(const uint4*)(src + 1024);
            uint4 vv = *(const uint4*)(src + 2048);
            *(uint4*)(lk + key * 72 + dc * 8) = kk;
            uint2* vd = (uint2*)(lv + key * 68 + dc * 8);
            vd[0] = make_uint2(vv.x, vv.y);
            vd[1] = make_uint2(vv.z, vv.w);
        }
        __syncthreads();

        f32x4_t s[4];
#pragma unroll
        for (int sub = 0; sub < 4; ++sub) {
            const ushort_t* krow = lk + (16 * sub + r16) * 72;
            bf16x8_t kb0 = *(const bf16x8_t*)(krow + g * 8);
            bf16x8_t kb1 = *(const bf16x8_t*)(krow + 32 + g * 8);
            f32x4_t z = {};
            z = __builtin_amdgcn_mfma_f32_16x16x32_bf16(qa[0], kb0, z, 0, 0, 0);
            z = __builtin_amdgcn_mfma_f32_16x16x32_bf16(qa[1], kb1, z, 0, 0, 0);
            s[sub] = z;
        }

        float alpha[4];
#pragma unroll
        for (int reg = 0; reg < 4; ++reg) {
            const int i = q0 + 16 * w + g * 4 + reg;
            float rm = -1e30f;
#pragma unroll
            for (int sub = 0; sub < 4; ++sub) {
                const int j = kt0 + 16 * sub + r16;
                const int d = i - j;
                const bool valid = (d <= 128) && (d >= -128);
                float v = valid ? s[sub][reg] * 0.125f : -1e30f;
                s[sub][reg] = v;
                rm = fmaxf(rm, v);
            }
#pragma unroll
            for (int msk = 1; msk < 16; msk <<= 1) rm = fmaxf(rm, __shfl_xor(rm, msk));
            const float mnew = fmaxf(mrow[reg], rm);
            alpha[reg] = __expf(mrow[reg] - mnew);
            mrow[reg] = mnew;
            float rs = 0.f;
#pragma unroll
            for (int sub = 0; sub < 4; ++sub) {
                float p = __expf(s[sub][reg] - mnew);
                s[sub][reg] = p;
                rs += p;
            }
#pragma unroll
            for (int msk = 1; msk < 16; msk <<= 1) rs += __shfl_xor(rs, msk);
            lrow[reg] = lrow[reg] * alpha[reg] + rs;
#pragma unroll
            for (int dd = 0; dd < 4; ++dd) O[dd][reg] *= alpha[reg];
        }

        ushort_t* pw = lp + w * 16 * 72;
#pragma unroll
        for (int sub = 0; sub < 4; ++sub)
#pragma unroll
            for (int reg = 0; reg < 4; ++reg)
                pw[(g * 4 + reg) * 72 + 16 * sub + r16] = f2b(s[sub][reg]);

        bf16x8_t pa0 = *(const bf16x8_t*)(pw + r16 * 72 + g * 8);
        bf16x8_t pa1 = *(const bf16x8_t*)(pw + r16 * 72 + 32 + g * 8);
        const __bf16* lvb = (const __bf16*)lv;
#pragma unroll
        for (int dd = 0; dd < 4; ++dd) {
            bf16x8_t vb0, vb1;
#pragma unroll
            for (int j = 0; j < 8; ++j) {
                vb0[j] = lvb[(g * 8 + j) * 68 + dd * 16 + r16];
                vb1[j] = lvb[(32 + g * 8 + j) * 68 + dd * 16 + r16];
            }
            O[dd] = __builtin_amdgcn_mfma_f32_16x16x32_bf16(pa0, vb0, O[dd], 0, 0, 0);
            O[dd] = __builtin_amdgcn_mfma_f32_16x16x32_bf16(pa1, vb1, O[dd], 0, 0, 0);
        }
        __syncthreads();
    }

#pragma unroll
    for (int reg = 0; reg < 4; ++reg) {
        const float inv = 1.0f / lrow[reg];
        const int i = q0 + 16 * w + g * 4 + reg;
        ushort_t* orow = attn + ((size_t)(bb * S + i)) * 1024 + (size_t)h * 64;
#pragma unroll
        for (int dd = 0; dd < 4; ++dd)
            orow[dd * 16 + r16] = f2b(O[dd][reg] * inv);
    }
}

// ---------------------------------------------------------------- LayerNorm + split-K reduce row (r0-proven body)
template <int NP>
static __device__ void ln_row(float* red,
                              const ushort_t* __restrict__ p0,
                              const ushort_t* __restrict__ p1,
                              const ushort_t* __restrict__ p2,
                              const ushort_t* __restrict__ p3,
                              const float* __restrict__ bias,
                              const float* __restrict__ res,
                              const float* __restrict__ g,
                              const float* __restrict__ bta,
                              float* __restrict__ outf,
                              ushort_t* __restrict__ outb,
                              int row, int t) {
    const size_t idx = (size_t)row * 256 + t;
    float4 v;
    {
        ushort4 a = ((const ushort4*)p0)[idx];
        ushort4 b = ((const ushort4*)p1)[idx];
        v.x = b2f(a.x) + b2f(b.x);
        v.y = b2f(a.y) + b2f(b.y);
        v.z = b2f(a.z) + b2f(b.z);
        v.w = b2f(a.w) + b2f(b.w);
    }
    if (NP == 4) {
        ushort4 a = ((const ushort4*)p2)[idx];
        ushort4 b = ((const ushort4*)p3)[idx];
        v.x += b2f(a.x) + b2f(b.x);
        v.y += b2f(a.y) + b2f(b.y);
        v.z += b2f(a.z) + b2f(b.z);
        v.w += b2f(a.w) + b2f(b.w);
    }
    {
        float4 bb = ((const float4*)bias)[t];
        float4 rr = ((const float4*)res)[idx];
        v.x += bb.x + rr.x; v.y += bb.y + rr.y; v.z += bb.z + rr.z; v.w += bb.w + rr.w;
    }

    float s = v.x + v.y + v.z + v.w;
    float s2 = v.x * v.x + v.y * v.y + v.z * v.z + v.w * v.w;
#pragma unroll
    for (int off = 32; off > 0; off >>= 1) {
        s += __shfl_down(s, off);
        s2 += __shfl_down(s2, off);
    }
    const int w = t >> 6, lane = t & 63;
    if (lane == 0) { red[w] = s; red[4 + w] = s2; }
    __syncthreads();
    float S1 = red[0] + red[1] + red[2] + red[3];
    float S2 = red[4] + red[5] + red[6] + red[7];
    float mean = S1 * (1.f / 1024.f);
    float var = S2 * (1.f / 1024.f) - mean * mean;
    float r = rsqrtf(var + 1e-5f);
    float4 gg = ((const float4*)g)[t];
    float4 bb = ((const float4*)bta)[t];
    float4 o;
    o.x = (v.x - mean) * r * gg.x + bb.x;
    o.y = (v.y - mean) * r * gg.y + bb.y;
    o.z = (v.z - mean) * r * gg.z + bb.z;
    o.w = (v.w - mean) * r * gg.w + bb.w;
    ((float4*)outf)[idx] = o;
    if (outb) {
        ushort4 ob;
        ob.x = f2b(o.x); ob.y = f2b(o.y); ob.z = f2b(o.z); ob.w = f2b(o.w);
        ((ushort4*)outb)[idx] = ob;
    }
    __syncthreads();   // guard red[] reuse across grid-stride row iterations
}

// ---------------------------------------------------------------- mega kernel (single launch + software grid barrier)
struct MegaArgs {
    const float *x, *in_proj_w, *in_proj_b, *out_proj_w, *out_proj_b;
    const float *ln1_g, *ln1_b, *w1, *b1, *w2, *b2, *ln2_g, *ln2_b;
    ushort_t *xb, *wqkvb, *woutb, *w1b, *w2b, *qkvb, *attnb, *x2b, *hb;
    float *x2f, *outf;
    ushort_t *op_p0, *op_p1, *f2_p0, *f2_p1, *f2_p2, *f2_p3;
    uint_t *bcnt, *bgen;
};

__global__ __launch_bounds__(256, 2) void mega(MegaArgs a) {
    __shared__ __align__(16) ushort_t smem[16384];   // 32 KiB, re-carved per phase
    const int t = threadIdx.x;
    const int nb = gridDim.x;                        // 512 = 2 blocks/CU (guaranteed by launch_bounds)
    const int tid = blockIdx.x * 256 + t;
    const int nthr = nb * 256;

    // phase 0: f32 -> bf16 casts of x + all weights
    cast_arr(a.x,          a.xb,    1048576, tid, nthr);
    cast_arr(a.in_proj_w,  a.wqkvb,  786432, tid, nthr);
    cast_arr(a.out_proj_w, a.woutb,  262144, tid, nthr);
    cast_arr(a.w1,         a.w1b,   1048576, tid, nthr);
    cast_arr(a.w2,         a.w2b,   1048576, tid, nthr);
    gsync(a.bcnt, a.bgen, nb);

    // phase 1: qkv = x @ in_proj_w.T + b   (768 tiles, old grid 24x32)
    for (int lid = blockIdx.x; lid < 768; lid += nb)
        gemm_tile<EPI_BIAS | EPI_OUTB>(smem, smem + 8192, a.xb, a.wqkvb, a.in_proj_b,
                                       nullptr, nullptr, nullptr, nullptr, a.qkvb,
                                       3072, 1024, 1024, lid, 24, 32, 1, t);
    gsync(a.bcnt, a.bgen, nb);

    // phase 2: banded flash attention (1024 tiles, old grid 32x16x2)
    for (int lid = blockIdx.x; lid < 1024; lid += nb)
        flash_tile(smem, smem + 4608, smem + 8960, a.qkvb, a.attnb, lid, t);
    gsync(a.bcnt, a.bgen, nb);

    // phase 3: out_proj split-K x2 (512 tiles, old grid 8x32x2)
    for (int lid = blockIdx.x; lid < 512; lid += nb)
        gemm_tile<EPI_PART>(smem, smem + 8192, a.attnb, a.woutb, nullptr,
                            a.op_p0, a.op_p1, nullptr, nullptr, nullptr,
                            1024, 512, 1024, lid, 8, 32, 2, t);
    gsync(a.bcnt, a.bgen, nb);

    // phase 4: x2 = LN1(p0+p1 + out_proj_b + x)
    for (int row = blockIdx.x; row < 4096; row += nb)
        ln_row<2>((float*)smem, a.op_p0, a.op_p1, nullptr, nullptr,
                  a.out_proj_b, a.x, a.ln1_g, a.ln1_b, a.x2f, a.x2b, row, t);
    gsync(a.bcnt, a.bgen, nb);

    // phase 5: h = relu(x2 @ w1.T + b1) (1024 tiles, old grid 32x32)
    for (int lid = blockIdx.x; lid < 1024; lid += nb)
        gemm_tile<EPI_BIAS | EPI_RELU | EPI_OUTB>(smem, smem + 8192, a.x2b, a.w1b, a.b1,
                                                  nullptr, nullptr, nullptr, nullptr, a.hb,
                                                  4096, 1024, 1024, lid, 32, 32, 1, t);
    gsync(a.bcnt, a.bgen, nb);

    // phase 6: FFN2 split-K x4 (1024 tiles, old grid 8x32x4)
    for (int lid = blockIdx.x; lid < 1024; lid += nb)
        gemm_tile<EPI_PART>(smem, smem + 8192, a.hb, a.w2b, nullptr,
                            a.f2_p0, a.f2_p1, a.f2_p2, a.f2_p3, nullptr,
                            1024, 1024, 4096, lid, 8, 32, 4, t);
    gsync(a.bcnt, a.bgen, nb);

    // phase 7: out = LN2(p0..p3 + b2 + x2)
    for (int row = blockIdx.x; row < 4096; row += nb)
        ln_row<4>((float*)smem, a.f2_p0, a.f2_p1, a.f2_p2, a.f2_p3,
                  a.b2, a.x2f, a.ln2_g, a.ln2_b, a.outf, nullptr, row, t);
}

// ---------------------------------------------------------------- launch
extern "C" void kernel_launch(void* const* d_in, const int* in_sizes, int n_in,
                              void* d_out, int out_size, void* d_ws, size_t ws_size,
                              hipStream_t stream) {
    char* ws = (char*)d_ws;
    MegaArgs a;
    a.x          = (const float*)d_in[0];
    a.in_proj_w  = (const float*)d_in[1];
    a.in_proj_b  = (const float*)d_in[2];
    a.out_proj_w = (const float*)d_in[3];
    a.out_proj_b = (const float*)d_in[4];
    a.ln1_g      = (const float*)d_in[5];
    a.ln1_b      = (const float*)d_in[6];
    a.w1         = (const float*)d_in[7];
    a.b1         = (const float*)d_in[8];
    a.w2         = (const float*)d_in[9];
    a.b2         = (const float*)d_in[10];
    a.ln2_g      = (const float*)d_in[11];
    a.ln2_b      = (const float*)d_in[12];

    a.xb    = (ushort_t*)(ws + (0ull << 20));    //  8 MB: x bf16       (4096x1024)
    a.wqkvb = (ushort_t*)(ws + (8ull << 20));    //  6 MB: in_proj_w    (3072x1024)
    a.woutb = (ushort_t*)(ws + (14ull << 20));   //  2 MB: out_proj_w   (1024x1024)
    a.w1b   = (ushort_t*)(ws + (16ull << 20));   //  8 MB: w1           (4096x1024)
    a.w2b   = (ushort_t*)(ws + (24ull << 20));   //  8 MB: w2           (1024x4096)
    a.qkvb  = (ushort_t*)(ws + (32ull << 20));   // 24 MB: qkv bf16     (4096x3072)
    a.attnb = (ushort_t*)(ws + (56ull << 20));   //  8 MB: attn bf16    (4096x1024)
    a.x2f   = (float*)(ws + (80ull << 20));      // 16 MB: x2 f32
    a.x2b   = (ushort_t*)(ws + (96ull << 20));   //  8 MB: x2 bf16
    a.hb    = (ushort_t*)(ws + (104ull << 20));  // 32 MB: relu hidden  (4096x4096)
    // bf16 split-K partials (8 MB each) in regions dead at their phase:
    a.op_p0 = (ushort_t*)(ws + (64ull << 20));   // out_proj p0
    a.op_p1 = (ushort_t*)(ws + (72ull << 20));   // out_proj p1
    a.f2_p0 = (ushort_t*)(ws + (0ull << 20));    // FFN2 p0 (xb dead)
    a.f2_p1 = (ushort_t*)(ws + (8ull << 20));    // FFN2 p1 (wqkvb dead)
    a.f2_p2 = (ushort_t*)(ws + (32ull << 20));   // FFN2 p2 (qkvb dead)
    a.f2_p3 = (ushort_t*)(ws + (40ull << 20));   // FFN2 p3 (qkvb dead)
    a.outf  = (float*)d_out;

    // barrier counters: past-hb workspace if available, else d_out tail
    // (d_out tail is rewritten by phase 7 after the last barrier use; the
    // harness memsets d_out before each launch and we memset again here).
    uint_t* bar;
    if (ws_size >= (137ull << 20)) bar = (uint_t*)(ws + (136ull << 20));
    else bar = (uint_t*)((char*)d_out + 16ull * 1024 * 1024 - 64);
    a.bcnt = bar;
    a.bgen = bar + 1;
    hipMemsetAsync(bar, 0, 8, stream);

    (void)in_sizes; (void)n_in; (void)out_size;

    hipLaunchKernelGGL(mega, dim3(512), dim3(256), 0, stream, a);
}

// Round 6
// 298.845 us; speedup vs baseline: 2.4693x; 2.4693x over previous
//
#include <hip/hip_runtime.h>
#include <hip/hip_bf16.h>

#define AS1 __attribute__((address_space(1)))
#define AS3 __attribute__((address_space(3)))

typedef __bf16 bf16x8_t __attribute__((ext_vector_type(8)));
typedef float f32x4_t __attribute__((ext_vector_type(4)));
typedef unsigned short ushort_t;
typedef unsigned int uint_t;

static __device__ __forceinline__ ushort_t f2b(float f) {
    __hip_bfloat16 h = __float2bfloat16(f);
    return __builtin_bit_cast(unsigned short, h);
}
static __device__ __forceinline__ float b2f(ushort_t u) {
    return __uint_as_float((uint_t)u << 16);
}

// ---------------------------------------------------------------- fused casts (one launch)
struct CastArgs {
    const float* src[5];
    ushort_t* dst[5];
    int cum[6];   // prefix sums of float4-group counts
};

__global__ __launch_bounds__(256) void cast_all(CastArgs a) {
    const int i = blockIdx.x * 256 + threadIdx.x;
    if (i >= a.cum[5]) return;
    int s = 0;
#pragma unroll
    for (int k = 1; k < 5; ++k) s += (i >= a.cum[k]);
    const int idx = i - a.cum[s];
    float4 v = ((const float4*)a.src[s])[idx];
    ushort4 o;
    o.x = f2b(v.x); o.y = f2b(v.y); o.z = f2b(v.z); o.w = f2b(v.w);
    ((ushort4*)a.dst[s])[idx] = o;
}

// ---------------------------------------------------------------- bf16 MFMA GEMM, BK=64
// r0-proven structure: 128x128 tile, 4 waves, 2-barrier K-loop (~838 TF).
// C(MxN) = A(MxK) @ B^T (B stored NxK row-major), epilogue per FLAGS.
// LDS rows are 64 elems (128 B = all 32 banks); XOR-swizzle which global 16B
// chunk each lane stages (col3 ^ (row&7)); frag reads spread over all banks.
// Split-K over z (writes bf16 partial to pb.p[z] when EPI_PART). XCD swizzle:
// each XCD owns a contiguous m-stripe, n fastest -> A panels L2-hot.
#define EPI_BIAS 1
#define EPI_RELU 2
#define EPI_PART 8
#define EPI_OUTB 16

struct PB { ushort_t* p[4]; };

template <int F>
__global__ __launch_bounds__(256, 2) void gemm_bt(const ushort_t* __restrict__ A,
                                                  const ushort_t* __restrict__ B,
                                                  const float* __restrict__ bias,
                                                  PB pb,
                                                  ushort_t* __restrict__ outb,
                                                  int M, int N, int Kc, int ld) {
    __shared__ ushort_t la[128 * 64];
    __shared__ ushort_t lb[128 * 64];
    const int t = threadIdx.x;

    // XCD-aware swizzle (grid.x*grid.y*grid.z divisible by 8, grid.y by 8)
    const int nx = gridDim.x, ny = gridDim.y, nz = gridDim.z;
    const int lid = blockIdx.x + nx * (blockIdx.y + ny * blockIdx.z);
    const int xcd = lid & 7;
    const int slot = lid >> 3;
    const int n_i = slot % nx;
    const int rest = slot / nx;
    const int z = rest % nz;
    const int m_i = xcd * (ny >> 3) + rest / nz;

    const int n0 = n_i * 128;
    const int m0 = m_i * 128;
    const int k0 = z * Kc;
    const int lane = t & 63;
    const int w = t >> 6;
    const int wr = w >> 1, wc = w & 1;
    const int r16 = lane & 15, kq = lane >> 4;

    f32x4_t acc[4][4] = {};

    // staging source offsets (k-invariant): pass p stages 16B chunk
    // c = t+256p -> LDS slot c; global col-chunk is XOR-swizzled.
    size_t aoff[4], boff[4];
#pragma unroll
    for (int p = 0; p < 4; ++p) {
        const int c = t + 256 * p;
        const int row = c >> 3, cc = c & 7;
        const int gcol = (cc ^ (row & 7)) * 8;
        aoff[p] = (size_t)(m0 + row) * ld + gcol + k0;
        boff[p] = (size_t)(n0 + row) * ld + gcol + k0;
    }

    for (int kk = 0; kk < Kc; kk += 64) {
#pragma unroll
        for (int p = 0; p < 4; ++p) {
            __builtin_amdgcn_global_load_lds((AS1 void*)(A + aoff[p] + kk),
                                             (AS3 void*)(la + (t + 256 * p) * 8), 16, 0, 0);
            __builtin_amdgcn_global_load_lds((AS1 void*)(B + boff[p] + kk),
                                             (AS3 void*)(lb + (t + 256 * p) * 8), 16, 0, 0);
        }
        __syncthreads();
#pragma unroll
        for (int half = 0; half < 2; ++half) {
            const int sw = ((half * 4 + kq) ^ (r16 & 7)) * 8;
            bf16x8_t af[4], bfr[4];
#pragma unroll
            for (int mi = 0; mi < 4; ++mi)
                af[mi] = *(const bf16x8_t*)(la + (wr * 64 + mi * 16 + r16) * 64 + sw);
#pragma unroll
            for (int ni = 0; ni < 4; ++ni)
                bfr[ni] = *(const bf16x8_t*)(lb + (wc * 64 + ni * 16 + r16) * 64 + sw);
#pragma unroll
            for (int mi = 0; mi < 4; ++mi)
#pragma unroll
                for (int ni = 0; ni < 4; ++ni)
                    acc[mi][ni] = __builtin_amdgcn_mfma_f32_16x16x32_bf16(af[mi], bfr[ni], acc[mi][ni], 0, 0, 0);
        }
        __syncthreads();
    }

    ushort_t* po = (F & EPI_PART) ? pb.p[z] : outb;
#pragma unroll
    for (int mi = 0; mi < 4; ++mi) {
#pragma unroll
        for (int ni = 0; ni < 4; ++ni) {
            const int row = m0 + wr * 64 + mi * 16 + kq * 4;
            const int col = n0 + wc * 64 + ni * 16 + r16;
            float bv = (F & EPI_BIAS) ? bias[col] : 0.f;
#pragma unroll
            for (int i = 0; i < 4; ++i) {
                float v = acc[mi][ni][i] + bv;
                const size_t off = (size_t)(row + i) * N + col;
                if (F & EPI_RELU) v = fmaxf(v, 0.f);
                po[off] = f2b(v);
            }
        }
    }
}

// ---------------------------------------------------------------- MFMA banded flash attention
// qkv: (B*S, 3072) bf16 rows [q | k | v], head h owns cols h*64..h*64+63 of each third.
__global__ __launch_bounds__(256, 4) void flash_mfma(const ushort_t* __restrict__ qkv,
                                                     ushort_t* __restrict__ attn) {
    const int S = 2048;
    const int h = blockIdx.y, bb = blockIdx.z;
    const int q0 = blockIdx.x * 64;
    const int t = threadIdx.x;
    const int w = t >> 6, lane = t & 63;
    const int r16 = lane & 15, g = lane >> 4;

    __shared__ ushort_t lk[64 * 72];
    __shared__ ushort_t lv[64 * 68];
    __shared__ ushort_t lp[4 * 16 * 72];

    const ushort_t* base = qkv + (size_t)bb * S * 3072 + (size_t)h * 64;

    bf16x8_t qa[2];
    {
        const ushort_t* qrow = base + (size_t)(q0 + 16 * w + r16) * 3072;
        qa[0] = *(const bf16x8_t*)(qrow + g * 8);
        qa[1] = *(const bf16x8_t*)(qrow + 32 + g * 8);
    }

    f32x4_t O[4] = {};
    float mrow[4] = {-1e30f, -1e30f, -1e30f, -1e30f};
    float lrow[4] = {0.f, 0.f, 0.f, 0.f};

    for (int it = 0; it < 5; ++it) {
        const int kt0 = q0 - 128 + 64 * it;
        if (kt0 < 0 || kt0 >= S) continue;

#pragma unroll
        for (int pass = 0; pass < 2; ++pass) {
            const int c = t + 256 * pass;
            const int key = c >> 3, dc = c & 7;
            const ushort_t* src = base + (size_t)(kt0 + key) * 3072 + dc * 8;
            uint4 kk = *(const uint4*)(src + 1024);
            uint4 vv = *(const uint4*)(src + 2048);
            *(uint4*)(lk + key * 72 + dc * 8) = kk;
            uint2* vd = (uint2*)(lv + key * 68 + dc * 8);
            vd[0] = make_uint2(vv.x, vv.y);
            vd[1] = make_uint2(vv.z, vv.w);
        }
        __syncthreads();

        f32x4_t s[4];
#pragma unroll
        for (int sub = 0; sub < 4; ++sub) {
            const ushort_t* krow = lk + (16 * sub + r16) * 72;
            bf16x8_t kb0 = *(const bf16x8_t*)(krow + g * 8);
            bf16x8_t kb1 = *(const bf16x8_t*)(krow + 32 + g * 8);
            f32x4_t z = {};
            z = __builtin_amdgcn_mfma_f32_16x16x32_bf16(qa[0], kb0, z, 0, 0, 0);
            z = __builtin_amdgcn_mfma_f32_16x16x32_bf16(qa[1], kb1, z, 0, 0, 0);
            s[sub] = z;
        }

        float alpha[4];
#pragma unroll
        for (int reg = 0; reg < 4; ++reg) {
            const int i = q0 + 16 * w + g * 4 + reg;
            float rm = -1e30f;
#pragma unroll
            for (int sub = 0; sub < 4; ++sub) {
                const int j = kt0 + 16 * sub + r16;
                const int d = i - j;
                const bool valid = (d <= 128) && (d >= -128);
                float v = valid ? s[sub][reg] * 0.125f : -1e30f;
                s[sub][reg] = v;
                rm = fmaxf(rm, v);
            }
#pragma unroll
            for (int msk = 1; msk < 16; msk <<= 1) rm = fmaxf(rm, __shfl_xor(rm, msk));
            const float mnew = fmaxf(mrow[reg], rm);
            alpha[reg] = __expf(mrow[reg] - mnew);
            mrow[reg] = mnew;
            float rs = 0.f;
#pragma unroll
            for (int sub = 0; sub < 4; ++sub) {
                float p = __expf(s[sub][reg] - mnew);
                s[sub][reg] = p;
                rs += p;
            }
#pragma unroll
            for (int msk = 1; msk < 16; msk <<= 1) rs += __shfl_xor(rs, msk);
            lrow[reg] = lrow[reg] * alpha[reg] + rs;
#pragma unroll
            for (int dd = 0; dd < 4; ++dd) O[dd][reg] *= alpha[reg];
        }

        ushort_t* pw = lp + w * 16 * 72;
#pragma unroll
        for (int sub = 0; sub < 4; ++sub)
#pragma unroll
            for (int reg = 0; reg < 4; ++reg)
                pw[(g * 4 + reg) * 72 + 16 * sub + r16] = f2b(s[sub][reg]);

        bf16x8_t pa0 = *(const bf16x8_t*)(pw + r16 * 72 + g * 8);
        bf16x8_t pa1 = *(const bf16x8_t*)(pw + r16 * 72 + 32 + g * 8);
        const __bf16* lvb = (const __bf16*)lv;
#pragma unroll
        for (int dd = 0; dd < 4; ++dd) {
            bf16x8_t vb0, vb1;
#pragma unroll
            for (int j = 0; j < 8; ++j) {
                vb0[j] = lvb[(g * 8 + j) * 68 + dd * 16 + r16];
                vb1[j] = lvb[(32 + g * 8 + j) * 68 + dd * 16 + r16];
            }
            O[dd] = __builtin_amdgcn_mfma_f32_16x16x32_bf16(pa0, vb0, O[dd], 0, 0, 0);
            O[dd] = __builtin_amdgcn_mfma_f32_16x16x32_bf16(pa1, vb1, O[dd], 0, 0, 0);
        }
        __syncthreads();
    }

#pragma unroll
    for (int reg = 0; reg < 4; ++reg) {
        const float inv = 1.0f / lrow[reg];
        const int i = q0 + 16 * w + g * 4 + reg;
        ushort_t* orow = attn + ((size_t)(bb * S + i)) * 1024 + (size_t)h * 64;
#pragma unroll
        for (int dd = 0; dd < 4; ++dd)
            orow[dd * 16 + r16] = f2b(O[dd][reg] * inv);
    }
}

// ---------------------------------------------------------------- LayerNorm + split-K reduce
// v = sum(bf16 partials) + bias + res -> LN -> outf (f32, optional) / outb (bf16, optional).
// RESB: residual is bf16 (ushort) instead of f32.
template <int NP, int RESB>
__global__ __launch_bounds__(256) void ln_red(const ushort_t* __restrict__ p0,
                                              const ushort_t* __restrict__ p1,
                                              const ushort_t* __restrict__ p2,
                                              const ushort_t* __restrict__ p3,
                                              const float* __restrict__ bias,
                                              const void* __restrict__ res,
                                              const float* __restrict__ g,
                                              const float* __restrict__ bta,
                                              float* __restrict__ outf,
                                              ushort_t* __restrict__ outb) {
    const int row = blockIdx.x;
    const int t = threadIdx.x;
    const size_t idx = (size_t)row * 256 + t;
    float4 v;
    {
        ushort4 a = ((const ushort4*)p0)[idx];
        ushort4 b = ((const ushort4*)p1)[idx];
        v.x = b2f(a.x) + b2f(b.x);
        v.y = b2f(a.y) + b2f(b.y);
        v.z = b2f(a.z) + b2f(b.z);
        v.w = b2f(a.w) + b2f(b.w);
    }
    if (NP == 4) {
        ushort4 a = ((const ushort4*)p2)[idx];
        ushort4 b = ((const ushort4*)p3)[idx];
        v.x += b2f(a.x) + b2f(b.x);
        v.y += b2f(a.y) + b2f(b.y);
        v.z += b2f(a.z) + b2f(b.z);
        v.w += b2f(a.w) + b2f(b.w);
    }
    {
        float4 bb = ((const float4*)bias)[t];
        v.x += bb.x; v.y += bb.y; v.z += bb.z; v.w += bb.w;
    }
    if (RESB) {
        ushort4 rr = ((const ushort4*)res)[idx];
        v.x += b2f(rr.x); v.y += b2f(rr.y); v.z += b2f(rr.z); v.w += b2f(rr.w);
    } else {
        float4 rr = ((const float4*)res)[idx];
        v.x += rr.x; v.y += rr.y; v.z += rr.z; v.w += rr.w;
    }

    float s = v.x + v.y + v.z + v.w;
    float s2 = v.x * v.x + v.y * v.y + v.z * v.z + v.w * v.w;
#pragma unroll
    for (int off = 32; off > 0; off >>= 1) {
        s += __shfl_down(s, off);
        s2 += __shfl_down(s2, off);
    }
    __shared__ float red[8];
    const int w = t >> 6, lane = t & 63;
    if (lane == 0) { red[w] = s; red[4 + w] = s2; }
    __syncthreads();
    float S1 = red[0] + red[1] + red[2] + red[3];
    float S2 = red[4] + red[5] + red[6] + red[7];
    float mean = S1 * (1.f / 1024.f);
    float var = S2 * (1.f / 1024.f) - mean * mean;
    float r = rsqrtf(var + 1e-5f);
    float4 gg = ((const float4*)g)[t];
    float4 bb = ((const float4*)bta)[t];
    float4 o;
    o.x = (v.x - mean) * r * gg.x + bb.x;
    o.y = (v.y - mean) * r * gg.y + bb.y;
    o.z = (v.z - mean) * r * gg.z + bb.z;
    o.w = (v.w - mean) * r * gg.w + bb.w;
    if (outf) ((float4*)outf)[idx] = o;
    if (outb) {
        ushort4 ob;
        ob.x = f2b(o.x); ob.y = f2b(o.y); ob.z = f2b(o.z); ob.w = f2b(o.w);
        ((ushort4*)outb)[idx] = ob;
    }
}

// ---------------------------------------------------------------- launch
extern "C" void kernel_launch(void* const* d_in, const int* in_sizes, int n_in,
                              void* d_out, int out_size, void* d_ws, size_t ws_size,
                              hipStream_t stream) {
    const float* x          = (const float*)d_in[0];
    const float* in_proj_w  = (const float*)d_in[1];
    const float* in_proj_b  = (const float*)d_in[2];
    const float* out_proj_w = (const float*)d_in[3];
    const float* out_proj_b = (const float*)d_in[4];
    const float* ln1_g      = (const float*)d_in[5];
    const float* ln1_b      = (const float*)d_in[6];
    const float* w1         = (const float*)d_in[7];
    const float* b1         = (const float*)d_in[8];
    const float* w2         = (const float*)d_in[9];
    const float* b2         = (const float*)d_in[10];
    const float* ln2_g      = (const float*)d_in[11];
    const float* ln2_b      = (const float*)d_in[12];

    char* ws = (char*)d_ws;
    ushort_t* xb    = (ushort_t*)(ws + (0ull << 20));    //  8 MB: x bf16       (4096x1024)
    ushort_t* wqkvb = (ushort_t*)(ws + (8ull << 20));    //  6 MB: in_proj_w    (3072x1024)
    ushort_t* woutb = (ushort_t*)(ws + (14ull << 20));   //  2 MB: out_proj_w   (1024x1024)
    ushort_t* w1b   = (ushort_t*)(ws + (16ull << 20));   //  8 MB: w1           (4096x1024)
    ushort_t* w2b   = (ushort_t*)(ws + (24ull << 20));   //  8 MB: w2           (1024x4096)
    ushort_t* qkvb  = (ushort_t*)(ws + (32ull << 20));   // 24 MB: qkv bf16     (4096x3072)
    ushort_t* attnb = (ushort_t*)(ws + (56ull << 20));   //  8 MB: attn bf16    (4096x1024)
    ushort_t* x2b   = (ushort_t*)(ws + (96ull << 20));   //  8 MB: x2 bf16
    ushort_t* hb    = (ushort_t*)(ws + (104ull << 20));  // 32 MB: relu hidden  (4096x4096)
    // bf16 split-K partials (8 MB each) in regions dead at their phase:
    ushort_t* op_p0 = (ushort_t*)(ws + (64ull << 20));   // out_proj p0
    ushort_t* op_p1 = (ushort_t*)(ws + (72ull << 20));   // out_proj p1
    ushort_t* f2_p0 = (ushort_t*)(ws + (0ull << 20));    // FFN2 p0 (xb dead)
    ushort_t* f2_p1 = (ushort_t*)(ws + (8ull << 20));    // FFN2 p1 (wqkvb dead)
    (void)in_sizes; (void)n_in; (void)out_size; (void)ws_size;

    // ---- one fused cast launch
    CastArgs ca;
    ca.src[0] = x;  ca.dst[0] = xb;
    ca.src[1] = in_proj_w;  ca.dst[1] = wqkvb;
    ca.src[2] = out_proj_w; ca.dst[2] = woutb;
    ca.src[3] = w1; ca.dst[3] = w1b;
    ca.src[4] = w2; ca.dst[4] = w2b;
    ca.cum[0] = 0;
    ca.cum[1] = 1048576;
    ca.cum[2] = 1048576 + 786432;
    ca.cum[3] = 1048576 + 786432 + 262144;
    ca.cum[4] = 1048576 + 786432 + 262144 + 1048576;
    ca.cum[5] = 1048576 + 786432 + 262144 + 1048576 + 1048576;
    cast_all<<<(ca.cum[5] + 255) / 256, 256, 0, stream>>>(ca);

    PB none = {{nullptr, nullptr, nullptr, nullptr}};

    // qkv = x @ in_proj_w.T + b   -> bf16
    gemm_bt<EPI_BIAS | EPI_OUTB><<<dim3(24, 32, 1), 256, 0, stream>>>(
        xb, wqkvb, in_proj_b, none, qkvb, 4096, 3072, 1024, 1024);

    // banded MFMA flash attention -> attnb bf16
    flash_mfma<<<dim3(32, 16, 2), 256, 0, stream>>>(qkvb, attnb);

    // out_proj split-K x2 -> bf16 partials
    PB op = {{op_p0, op_p1, nullptr, nullptr}};
    gemm_bt<EPI_PART><<<dim3(8, 32, 2), 256, 0, stream>>>(
        attnb, woutb, nullptr, op, nullptr, 4096, 1024, 512, 1024);

    // x2 = LN1(p0+p1 + out_proj_b + x) -> bf16 only (x2f eliminated)
    ln_red<2, 0><<<4096, 256, 0, stream>>>(op_p0, op_p1, nullptr, nullptr,
                                           out_proj_b, x, ln1_g, ln1_b,
                                           nullptr, x2b);

    // h = relu(x2 @ w1.T + b1) -> bf16
    gemm_bt<EPI_BIAS | EPI_RELU | EPI_OUTB><<<dim3(32, 32, 1), 256, 0, stream>>>(
        x2b, w1b, b1, none, hb, 4096, 4096, 1024, 1024);

    // FFN2 split-K x2 -> bf16 partials (Kc=2048; halves partial traffic vs x4)
    PB f2 = {{f2_p0, f2_p1, nullptr, nullptr}};
    gemm_bt<EPI_PART><<<dim3(8, 32, 2), 256, 0, stream>>>(
        hb, w2b, nullptr, f2, nullptr, 4096, 1024, 2048, 4096);

    // out = LN2(p0+p1 + b2 + x2b residual) -> f32 d_out
    ln_red<2, 1><<<4096, 256, 0, stream>>>(f2_p0, f2_p1, nullptr, nullptr,
                                           b2, x2b, ln2_g, ln2_b,
                                           (float*)d_out, nullptr);
}